// Round 10
// baseline (88.494 us; speedup 1.0000x reference)
//
#include <hip/hip_runtime.h>

constexpr int B_   = 4;
constexpr int NL   = 8192;
constexpr int NH   = 2048;
constexpr int CH   = 256;
constexpr int CL   = 128;
constexpr int CIN  = 384;
constexpr int COUT = 256;

typedef _Float16 f16;
typedef _Float16 f16x8 __attribute__((ext_vector_type(8)));
typedef float    f32x4 __attribute__((ext_vector_type(4)));

// Branchless top-3 insert (strict < == earliest-index-wins on ties).
#define BINS(d, h, B0, B1, B2, I0, I1, I2) do {                              \
    bool m2_ = (d) < (B2); B2 = m2_ ? (d) : B2; I2 = m2_ ? (h) : I2;         \
    bool m1_ = (B2) < (B1);                                                  \
    { float t_ = B1; int ti_ = I1;                                           \
      B1 = m1_ ? B2 : B1; I1 = m1_ ? I2 : I1;                                \
      B2 = m1_ ? t_ : B2; I2 = m1_ ? ti_ : I2; }                             \
    bool m0_ = (B1) < (B0);                                                  \
    { float t_ = B0; int ti_ = I0;                                           \
      B0 = m0_ ? B1 : B0; I0 = m0_ ? I1 : I0;                                \
      B1 = m0_ ? t_ : B1; I1 = m0_ ? ti_ : I1; }                             \
} while (0)

// ---------------------------------------------------------------------------
// K1: role-fused.
//   [0,2048):    3-NN quarter-range blocks. Block = (tile<<2)|qt; covers the
//                tile's 64 low points against h in [qt*512, qt*512+512).
//                Wave w scans a 128-h slice (pts[h] wave-uniform broadcast).
//                12-way slice-order merge -> top-3 (d2, idx) per point per
//                quarter, RAW to cdG/ciG (weights computed in K2).
//   [2048,2560): fhT transpose (B,CH,NH) f32 -> (B,NH,CH) f16.
//   [2560,2944): W f32 -> f16.
// 13.2 KB LDS; knn grid alone = 8 blocks/CU = 32 waves/CU.
// ---------------------------------------------------------------------------
__global__ __launch_bounds__(256) void knn_prep_kernel(
    const float* __restrict__ xyz_low, const float* __restrict__ xyz_high,
    const float* __restrict__ feat_high, const float* __restrict__ Wm,
    f16* __restrict__ fhT, f16* __restrict__ Wh,
    float* __restrict__ cdG, int* __restrict__ ciG)
{
    __shared__ __align__(16) char smraw[13184];
    const int bid = blockIdx.x, tid = threadIdx.x;

    if (bid < 2048) {
        float4*         pts = (float4*)smraw;                  // [0, 8192)
        float*          md  = (float*)(smraw + 8192);          // 64*13 f32
        unsigned short* mi  = (unsigned short*)(smraw + 11520);// 64*13 u16
        const int tile = bid >> 2, qt = bid & 3;
        const int b = tile >> 7, l0 = (tile & 127) * 64;
        const int w = tid >> 6, p = tid & 63;
        const int hbase = qt * 512;

        const float* xh = xyz_high + ((size_t)b * NH + hbase) * 3;
        for (int h = tid; h < 512; h += 256) {
            float x = xh[h * 3], yy = xh[h * 3 + 1], z = xh[h * 3 + 2];
            pts[h] = make_float4(x, yy, z, x * x + yy * yy + z * z);
        }
        __syncthreads();

        const float* xl = xyz_low + ((size_t)b * NL + l0 + p) * 3;
        const float lx = xl[0], ly = xl[1], lz = xl[2];
        const float sl = lx * lx + ly * ly + lz * lz;

        float b0 = 1e30f, b1 = 1e30f, b2 = 1e30f;
        int i0 = 0, i1 = 0, i2 = 0;
        const int h0 = w * 128;
        #pragma unroll 8
        for (int h = h0; h < h0 + 128; ++h) {
            float4 pt = pts[h];
            float d2 = fmaf(-2.0f, fmaf(lx, pt.x, fmaf(ly, pt.y, lz * pt.z)),
                            sl + pt.w);
            BINS(d2, h, b0, b1, b2, i0, i1, i2);
        }
        const int cb = p * 13 + w * 3;
        md[cb] = b0;     mi[cb] = (unsigned short)(hbase + i0);
        md[cb + 1] = b1; mi[cb + 1] = (unsigned short)(hbase + i1);
        md[cb + 2] = b2; mi[cb + 2] = (unsigned short)(hbase + i2);
        __syncthreads();

        if (tid < 64) {   // merge 12 in slice order (h ascending, tie-stable)
            float e0 = 1e30f, e1 = 1e30f, e2 = 1e30f;
            int j0 = 0, j1 = 0, j2 = 0;
            #pragma unroll
            for (int q = 0; q < 12; ++q) {
                float d = md[tid * 13 + q];
                int  ii = mi[tid * 13 + q];
                BINS(d, ii, e0, e1, e2, j0, j1, j2);
            }
            const size_t dst = (size_t)bid * 192 + tid;
            cdG[dst]       = e0; ciG[dst]       = j0;
            cdG[dst + 64]  = e1; ciG[dst + 64]  = j1;
            cdG[dst + 128] = e2; ciG[dst + 128] = j2;
        }
    } else if (bid < 2560) {
        float (*tt)[33] = (float(*)[33])smraw;
        const int tx = tid & 31, ty = tid >> 5;
        #pragma unroll
        for (int k = 0; k < 4; ++k) {
            const int u  = (bid - 2048) * 4 + k;       // 2048 tiles total
            const int ub = u >> 9, ut = u & 511;
            const int h0 = (ut & 63) * 32, c0 = (ut >> 6) * 32;
            #pragma unroll
            for (int pp = 0; pp < 4; ++pp)
                tt[ty + pp * 8][tx] =
                    feat_high[((size_t)ub * CH + c0 + ty + pp * 8) * NH + h0 + tx];
            __syncthreads();
            #pragma unroll
            for (int pp = 0; pp < 4; ++pp)
                fhT[((size_t)ub * NH + h0 + ty + pp * 8) * CH + c0 + tx] =
                    (f16)tt[tx][ty + pp * 8];
            __syncthreads();
        }
    } else {
        const int i = (bid - 2560) * 256 + tid;        // 384 blocks
        Wh[i] = (f16)Wm[i];
    }
}

// ---------------------------------------------------------------------------
// K2: tile 256(o) x 32(l), 1024 blocks. Merge the 4 quarter candidate
// triples (quarter order = h order, strict < -> exact tie semantics) ->
// weights; interp gather -> As (lane = point: conflict-free LDS writes);
// barrier-free K-loop (W A-frags from L2-hot global; B-frags from LDS As);
// bias into acc; per-block BN partials; fp16 y stores (64B/lane).
// ---------------------------------------------------------------------------
__global__ __launch_bounds__(256, 4) void gemm_kernel(
    const float* __restrict__ feat_low, const f16* __restrict__ fhT,
    const f16* __restrict__ Wh, const float* __restrict__ bias,
    const float* __restrict__ cdG, const int* __restrict__ ciG,
    f16* __restrict__ yh, float* __restrict__ ps, float* __restrict__ psq)
{
    // As [0,25088) = [32][392] f16 ; idxL [25088,25472) ; wL [25472,25856)
    __shared__ __align__(16) char smraw[25856];
    f16*   As   = (f16*)smraw;
    int*   idxL = (int*)(smraw + 25088);   // [3][32]
    float* wL   = (float*)(smraw + 25472); // [3][32]

    const int bid = blockIdx.x, tid = threadIdx.x;
    const int b = bid >> 8, l0 = (bid & 255) * 32;
    const int lane = tid & 63, w = tid >> 6;

    if (tid < 32) {   // cross-quarter merge + weights
        float e0 = 1e30f, e1 = 1e30f, e2 = 1e30f;
        int j0 = 0, j1 = 0, j2 = 0;
        const int poff = (bid & 1) * 32 + tid;         // point in 64-pt tile
        #pragma unroll
        for (int qt = 0; qt < 4; ++qt) {
            const size_t src = (size_t)((bid >> 1) * 4 + qt) * 192 + poff;
            #pragma unroll
            for (int q = 0; q < 3; ++q) {
                float d = cdG[src + q * 64];
                int  ii = ciG[src + q * 64];
                BINS(d, ii, e0, e1, e2, j0, j1, j2);
            }
        }
        float d0 = sqrtf(fmaxf(e0, 0.0f));
        float d1 = sqrtf(fmaxf(e1, 0.0f));
        float d2f = sqrtf(fmaxf(e2, 0.0f));
        float iw0 = 1.0f / fmaxf(d0, 1e-8f);
        float iw1 = 1.0f / fmaxf(d1, 1e-8f);
        float iw2 = 1.0f / fmaxf(d2f, 1e-8f);
        float sum = iw0 + iw1 + iw2;
        idxL[tid] = j0; idxL[32 + tid] = j1; idxL[64 + tid] = j2;
        wL[tid] = iw0 / sum; wL[32 + tid] = iw1 / sum; wL[64 + tid] = iw2 / sum;
    }
    __syncthreads();

    {   // prologue: lane = point p (consecutive rows -> no write conflicts)
        const int p = tid & 31, q = tid >> 5;          // q = 0..7
        const int j0 = idxL[p], j1 = idxL[32 + p], j2 = idxL[64 + p];
        const float u0 = wL[p], u1 = wL[32 + p], u2 = wL[64 + p];
        // interp channels [q*32, q*32+32)
        const f16* r0 = fhT + ((size_t)b * NH + j0) * CH + q * 32;
        const f16* r1 = fhT + ((size_t)b * NH + j1) * CH + q * 32;
        const f16* r2 = fhT + ((size_t)b * NH + j2) * CH + q * 32;
        #pragma unroll
        for (int j = 0; j < 4; ++j) {
            f16x8 v0 = *(const f16x8*)(r0 + j * 8);
            f16x8 v1 = *(const f16x8*)(r1 + j * 8);
            f16x8 v2 = *(const f16x8*)(r2 + j * 8);
            f16x8 o;
            #pragma unroll
            for (int e = 0; e < 8; ++e)
                o[e] = (f16)(u0 * (float)v0[e] + u1 * (float)v1[e]
                             + u2 * (float)v2[e]);
            *(f16x8*)&As[p * 392 + q * 32 + j * 8] = o;
        }
        // feat_low channels [q*16, q*16+16), direct from (B,CL,NL)
        const float* flb = feat_low + ((size_t)b * CL + q * 16) * NL + l0 + p;
        f16 tmp[16];
        #pragma unroll
        for (int i = 0; i < 16; ++i)
            tmp[i] = (f16)flb[(size_t)i * NL];
        #pragma unroll
        for (int j = 0; j < 2; ++j)
            *(f16x8*)&As[p * 392 + 256 + q * 16 + j * 8] =
                *(const f16x8*)&tmp[j * 8];
    }
    __syncthreads();

    f32x4 acc[4][2] = {};
    const int kb = (lane >> 4) * 8;
    const int r  = lane & 15;
    #pragma unroll
    for (int kt = 0; kt < 12; ++kt) {
        const int k0 = kt * 32;
        f16x8 a[4], bb[2];
        #pragma unroll
        for (int mi = 0; mi < 4; ++mi)
            a[mi] = *(const f16x8*)&Wh[(size_t)(w * 64 + mi * 16 + r) * CIN
                                       + k0 + kb];
        #pragma unroll
        for (int ni = 0; ni < 2; ++ni)
            bb[ni] = *(const f16x8*)&As[(ni * 16 + r) * 392 + k0 + kb];
        #pragma unroll
        for (int mi = 0; mi < 4; ++mi)
            #pragma unroll
            for (int ni = 0; ni < 2; ++ni)
                acc[mi][ni] = __builtin_amdgcn_mfma_f32_16x16x32_f16(
                    a[mi], bb[ni], acc[mi][ni], 0, 0, 0);
    }

    // bias into acc + per-block BN partials (no LDS touched)
    const int r4 = (lane >> 4) * 4, cl = lane & 15;
    #pragma unroll
    for (int mi = 0; mi < 4; ++mi) {
        #pragma unroll
        for (int j = 0; j < 4; ++j) {
            const int o = w * 64 + mi * 16 + r4 + j;
            const float bi = bias[o];
            float s = 0.0f, sq = 0.0f;
            #pragma unroll
            for (int ni = 0; ni < 2; ++ni) {
                acc[mi][ni][j] += bi;
                float v = acc[mi][ni][j];
                s += v; sq += v * v;
            }
            #pragma unroll
            for (int m = 1; m < 16; m <<= 1) {
                s  += __shfl_xor(s, m);
                sq += __shfl_xor(sq, m);
            }
            if (cl == 0) {
                ps [o * 1024 + bid] = s;
                psq[o * 1024 + bid] = sq;
            }
        }
    }
    __syncthreads();   // all As reads done -> safe to alias with Ys

    f16* Ys = (f16*)smraw;             // [256][40] f16 = 20480 B
    #pragma unroll
    for (int mi = 0; mi < 4; ++mi)
        #pragma unroll
        for (int j = 0; j < 4; ++j) {
            const int o = w * 64 + mi * 16 + r4 + j;
            #pragma unroll
            for (int ni = 0; ni < 2; ++ni)
                Ys[o * 40 + cl + ni * 16] = (f16)acc[mi][ni][j];
        }
    __syncthreads();
    {   // one 64B store per thread (64B-aligned line): o = tid
        f16* dst = yh + ((size_t)b * COUT + tid) * NL + l0;
        #pragma unroll
        for (int j = 0; j < 4; ++j)
            *(f16x8*)(dst + j * 8) = *(const f16x8*)&Ys[tid * 40 + j * 8];
    }
}

// ---------------------------------------------------------------------------
// K3: fused BN stats + apply + ReLU. Grid (COUT, B_): each block reduces its
// channel's 1024 partials (deterministic, redundant across the 4 b-blocks of
// a channel -> identical results) then applies to its (b,o) row of 8192.
// ---------------------------------------------------------------------------
__global__ __launch_bounds__(256) void stats_apply_kernel(
    const float* __restrict__ ps, const float* __restrict__ psq,
    const f16* __restrict__ yh,
    const float* __restrict__ gamma, const float* __restrict__ beta,
    float* __restrict__ y)
{
    const int o = blockIdx.x, b = blockIdx.y, tid = threadIdx.x;
    const int w = tid >> 6, lane = tid & 63;

    float s = 0.0f, q = 0.0f;
    #pragma unroll
    for (int k = 0; k < 4; ++k) {
        s += ps [o * 1024 + k * 256 + tid];
        q += psq[o * 1024 + k * 256 + tid];
    }
    #pragma unroll
    for (int m = 32; m > 0; m >>= 1) {
        s += __shfl_down(s, m);
        q += __shfl_down(q, m);
    }
    __shared__ float red[8];
    if (lane == 0) { red[w] = s; red[4 + w] = q; }
    __syncthreads();
    s = red[0] + red[1] + red[2] + red[3];
    q = red[4] + red[5] + red[6] + red[7];
    const float n  = (float)(B_ * NL);
    const float mu = s / n;
    const float rs = rsqrtf(q / n - mu * mu + 1e-5f);
    const float g  = gamma[o], be = beta[o];

    const f16* src = yh + ((size_t)b * COUT + o) * NL;
    float*     dst = y  + ((size_t)b * COUT + o) * NL;
    #pragma unroll
    for (int it = 0; it < 4; ++it) {
        const int base = it * 2048 + tid * 8;
        f16x8 v = *(const f16x8*)(src + base);
        float4 o1, o2;
        o1.x = fmaxf(fmaf(g, ((float)v[0] - mu) * rs, be), 0.0f);
        o1.y = fmaxf(fmaf(g, ((float)v[1] - mu) * rs, be), 0.0f);
        o1.z = fmaxf(fmaf(g, ((float)v[2] - mu) * rs, be), 0.0f);
        o1.w = fmaxf(fmaf(g, ((float)v[3] - mu) * rs, be), 0.0f);
        o2.x = fmaxf(fmaf(g, ((float)v[4] - mu) * rs, be), 0.0f);
        o2.y = fmaxf(fmaf(g, ((float)v[5] - mu) * rs, be), 0.0f);
        o2.z = fmaxf(fmaf(g, ((float)v[6] - mu) * rs, be), 0.0f);
        o2.w = fmaxf(fmaf(g, ((float)v[7] - mu) * rs, be), 0.0f);
        *(float4*)(dst + base)     = o1;
        *(float4*)(dst + base + 4) = o2;
    }
}

// ---------------------------------------------------------------------------
extern "C" void kernel_launch(void* const* d_in, const int* in_sizes, int n_in,
                              void* d_out, int out_size, void* d_ws, size_t ws_size,
                              hipStream_t stream)
{
    const float* xyz_low   = (const float*)d_in[0];
    const float* xyz_high  = (const float*)d_in[1];
    const float* feat_low  = (const float*)d_in[2];
    const float* feat_high = (const float*)d_in[3];
    const float* Wm        = (const float*)d_in[4];
    const float* bias      = (const float*)d_in[5];
    const float* gamma     = (const float*)d_in[6];
    const float* beta      = (const float*)d_in[7];
    float* y = (float*)d_out;

    float* ps   = (float*)d_ws;                        // 256*1024 f32
    float* psq  = ps + (size_t)COUT * 1024;            // 256*1024 f32
    float* cdG  = psq + (size_t)COUT * 1024;           // 2048*192 f32
    int*   ciG  = (int*)(cdG + (size_t)2048 * 192);    // 2048*192 i32
    f16*   Wh   = (f16*)(ciG + (size_t)2048 * 192);    // 256*384 f16
    f16*   fhT  = Wh + (size_t)COUT * CIN;             // 4*2048*256 f16 (4.2MB)
    f16*   yh   = fhT + (size_t)B_ * NH * CH;          // 4*256*8192 f16 (16.8MB)

    knn_prep_kernel<<<2944, 256, 0, stream>>>(
        xyz_low, xyz_high, feat_high, Wm, fhT, Wh, cdG, ciG);
    gemm_kernel<<<1024, 256, 0, stream>>>(
        feat_low, fhT, Wh, bias, cdG, ciG, yh, ps, psq);
    stats_apply_kernel<<<dim3(COUT, B_), 256, 0, stream>>>(
        ps, psq, yh, gamma, beta, y);
}

// Round 11
// 87.289 us; speedup vs baseline: 1.0138x; 1.0138x over previous
//
#include <hip/hip_runtime.h>

constexpr int B_   = 4;
constexpr int NL   = 8192;
constexpr int NH   = 2048;
constexpr int CH   = 256;
constexpr int CL   = 128;
constexpr int CIN  = 384;
constexpr int COUT = 256;

typedef _Float16 f16;
typedef _Float16 f16x8 __attribute__((ext_vector_type(8)));
typedef float    f32x4 __attribute__((ext_vector_type(4)));

// Branchless top-3 insert (strict < == earliest-index-wins on ties).
#define BINS(d, h, B0, B1, B2, I0, I1, I2) do {                              \
    bool m2_ = (d) < (B2); B2 = m2_ ? (d) : B2; I2 = m2_ ? (h) : I2;         \
    bool m1_ = (B2) < (B1);                                                  \
    { float t_ = B1; int ti_ = I1;                                           \
      B1 = m1_ ? B2 : B1; I1 = m1_ ? I2 : I1;                                \
      B2 = m1_ ? t_ : B2; I2 = m1_ ? ti_ : I2; }                             \
    bool m0_ = (B1) < (B0);                                                  \
    { float t_ = B0; int ti_ = I0;                                           \
      B0 = m0_ ? B1 : B0; I0 = m0_ ? I1 : I0;                                \
      B1 = m0_ ? t_ : B1; I1 = m0_ ? ti_ : I1; }                             \
} while (0)

// ---------------------------------------------------------------------------
// K1: role-fused (unchanged from R9/R10 proven version).
//   [0,2048):    3-NN quarter-range blocks -> raw top-3 (d2, idx) per point
//                per quarter into cdG/ciG.
//   [2048,2560): fhT transpose (B,CH,NH) f32 -> (B,NH,CH) f16.
//   [2560,2944): W f32 -> f16.
// ---------------------------------------------------------------------------
__global__ __launch_bounds__(256) void knn_prep_kernel(
    const float* __restrict__ xyz_low, const float* __restrict__ xyz_high,
    const float* __restrict__ feat_high, const float* __restrict__ Wm,
    f16* __restrict__ fhT, f16* __restrict__ Wh,
    float* __restrict__ cdG, int* __restrict__ ciG)
{
    __shared__ __align__(16) char smraw[13184];
    const int bid = blockIdx.x, tid = threadIdx.x;

    if (bid < 2048) {
        float4*         pts = (float4*)smraw;                  // [0, 8192)
        float*          md  = (float*)(smraw + 8192);          // 64*13 f32
        unsigned short* mi  = (unsigned short*)(smraw + 11520);// 64*13 u16
        const int tile = bid >> 2, qt = bid & 3;
        const int b = tile >> 7, l0 = (tile & 127) * 64;
        const int w = tid >> 6, p = tid & 63;
        const int hbase = qt * 512;

        const float* xh = xyz_high + ((size_t)b * NH + hbase) * 3;
        for (int h = tid; h < 512; h += 256) {
            float x = xh[h * 3], yy = xh[h * 3 + 1], z = xh[h * 3 + 2];
            pts[h] = make_float4(x, yy, z, x * x + yy * yy + z * z);
        }
        __syncthreads();

        const float* xl = xyz_low + ((size_t)b * NL + l0 + p) * 3;
        const float lx = xl[0], ly = xl[1], lz = xl[2];
        const float sl = lx * lx + ly * ly + lz * lz;

        float b0 = 1e30f, b1 = 1e30f, b2 = 1e30f;
        int i0 = 0, i1 = 0, i2 = 0;
        const int h0 = w * 128;
        #pragma unroll 8
        for (int h = h0; h < h0 + 128; ++h) {
            float4 pt = pts[h];
            float d2 = fmaf(-2.0f, fmaf(lx, pt.x, fmaf(ly, pt.y, lz * pt.z)),
                            sl + pt.w);
            BINS(d2, h, b0, b1, b2, i0, i1, i2);
        }
        const int cb = p * 13 + w * 3;
        md[cb] = b0;     mi[cb] = (unsigned short)(hbase + i0);
        md[cb + 1] = b1; mi[cb + 1] = (unsigned short)(hbase + i1);
        md[cb + 2] = b2; mi[cb + 2] = (unsigned short)(hbase + i2);
        __syncthreads();

        if (tid < 64) {   // merge 12 in slice order (h ascending, tie-stable)
            float e0 = 1e30f, e1 = 1e30f, e2 = 1e30f;
            int j0 = 0, j1 = 0, j2 = 0;
            #pragma unroll
            for (int q = 0; q < 12; ++q) {
                float d = md[tid * 13 + q];
                int  ii = mi[tid * 13 + q];
                BINS(d, ii, e0, e1, e2, j0, j1, j2);
            }
            const size_t dst = (size_t)bid * 192 + tid;
            cdG[dst]       = e0; ciG[dst]       = j0;
            cdG[dst + 64]  = e1; ciG[dst + 64]  = j1;
            cdG[dst + 128] = e2; ciG[dst + 128] = j2;
        }
    } else if (bid < 2560) {
        float (*tt)[33] = (float(*)[33])smraw;
        const int tx = tid & 31, ty = tid >> 5;
        #pragma unroll
        for (int k = 0; k < 4; ++k) {
            const int u  = (bid - 2048) * 4 + k;       // 2048 tiles total
            const int ub = u >> 9, ut = u & 511;
            const int h0 = (ut & 63) * 32, c0 = (ut >> 6) * 32;
            #pragma unroll
            for (int pp = 0; pp < 4; ++pp)
                tt[ty + pp * 8][tx] =
                    feat_high[((size_t)ub * CH + c0 + ty + pp * 8) * NH + h0 + tx];
            __syncthreads();
            #pragma unroll
            for (int pp = 0; pp < 4; ++pp)
                fhT[((size_t)ub * NH + h0 + ty + pp * 8) * CH + c0 + tx] =
                    (f16)tt[tx][ty + pp * 8];
            __syncthreads();
        }
    } else {
        const int i = (bid - 2560) * 256 + tid;        // 384 blocks
        Wh[i] = (f16)Wm[i];
    }
}

// ---------------------------------------------------------------------------
// K2: interpolation. 2048 blocks x 256 thr (16 points/block, max occupancy
// for gather MLP). Merge the 4 quarter candidate triples (h order, strict <
// -> exact sequential tie semantics) -> weights; gather fhT rows; write
// DENSE ficat (B,NL,256) fp16 (lives in d_out-as-scratch).
// ---------------------------------------------------------------------------
__global__ __launch_bounds__(256) void interp_kernel(
    const f16* __restrict__ fhT,
    const float* __restrict__ cdG, const int* __restrict__ ciG,
    f16* __restrict__ ficat)
{
    __shared__ int   idxL[3 * 16];
    __shared__ float wL[3 * 16];

    const int bid = blockIdx.x, tid = threadIdx.x;
    const int b = bid >> 9, l0 = (bid & 511) * 16;

    if (tid < 16) {   // cross-quarter merge + weights for 16 points
        float e0 = 1e30f, e1 = 1e30f, e2 = 1e30f;
        int j0 = 0, j1 = 0, j2 = 0;
        const int tile64 = bid >> 2;
        const int poff = (bid & 3) * 16 + tid;
        #pragma unroll
        for (int qt = 0; qt < 4; ++qt) {
            const size_t src = (size_t)(tile64 * 4 + qt) * 192 + poff;
            #pragma unroll
            for (int q = 0; q < 3; ++q) {
                float d = cdG[src + q * 64];
                int  ii = ciG[src + q * 64];
                BINS(d, ii, e0, e1, e2, j0, j1, j2);
            }
        }
        float d0 = sqrtf(fmaxf(e0, 0.0f));
        float d1 = sqrtf(fmaxf(e1, 0.0f));
        float d2f = sqrtf(fmaxf(e2, 0.0f));
        float iw0 = 1.0f / fmaxf(d0, 1e-8f);
        float iw1 = 1.0f / fmaxf(d1, 1e-8f);
        float iw2 = 1.0f / fmaxf(d2f, 1e-8f);
        float sum = iw0 + iw1 + iw2;
        idxL[tid] = j0; idxL[16 + tid] = j1; idxL[32 + tid] = j2;
        wL[tid] = iw0 / sum; wL[16 + tid] = iw1 / sum; wL[32 + tid] = iw2 / sum;
    }
    __syncthreads();

    const int p = tid & 15, q = tid >> 4;              // q = 0..15, 16 ch each
    const int j0 = idxL[p], j1 = idxL[16 + p], j2 = idxL[32 + p];
    const float u0 = wL[p], u1 = wL[16 + p], u2 = wL[32 + p];
    const f16* r0 = fhT + ((size_t)b * NH + j0) * CH + q * 16;
    const f16* r1 = fhT + ((size_t)b * NH + j1) * CH + q * 16;
    const f16* r2 = fhT + ((size_t)b * NH + j2) * CH + q * 16;
    f16* dst = ficat + (((size_t)b * NL + l0 + p) << 8) + q * 16;
    #pragma unroll
    for (int j = 0; j < 2; ++j) {
        f16x8 v0 = *(const f16x8*)(r0 + j * 8);
        f16x8 v1 = *(const f16x8*)(r1 + j * 8);
        f16x8 v2 = *(const f16x8*)(r2 + j * 8);
        f16x8 o;
        #pragma unroll
        for (int e = 0; e < 8; ++e)
            o[e] = (f16)(u0 * (float)v0[e] + u1 * (float)v1[e]
                         + u2 * (float)v2[e]);
        *(f16x8*)(dst + j * 8) = o;
    }
}

// ---------------------------------------------------------------------------
// K3: pure streaming GEMM. 512 blocks x 512 thr (8 waves; wave w owns 32
// o-rows x 64 l). As[64][392] staged coalesced (interp from dense ficat,
// feat_low direct); barrier-free 12-kt K-loop with W A-frags from L2-hot
// global; bias into acc; per-block BN partials; yh stores 128B/row.
// ---------------------------------------------------------------------------
__global__ __launch_bounds__(512) void gemm_kernel(
    const float* __restrict__ feat_low, const f16* __restrict__ ficat,
    const f16* __restrict__ Wh, const float* __restrict__ bias,
    f16* __restrict__ yh, float* __restrict__ ps, float* __restrict__ psq)
{
    // As [0,50176) = [64][392] f16 ; Ys aliases (36864 B)
    __shared__ __align__(16) char smraw[50176];
    f16* As = (f16*)smraw;

    const int bid = blockIdx.x, tid = threadIdx.x;
    const int b = bid >> 7, l0 = (bid & 127) * 64;
    const int lane = tid & 63, w = tid >> 6;

    {   // stage: row = tid>>3 (64 rows), q = tid&7 (48 ch each)
        const int row = tid >> 3, q = tid & 7;
        const f16* src = ficat + (((size_t)b * NL + l0 + row) << 8) + q * 32;
        #pragma unroll
        for (int j = 0; j < 4; ++j)
            *(f16x8*)&As[row * 392 + q * 32 + j * 8] =
                *(const f16x8*)(src + j * 8);
        const float* flb = feat_low + ((size_t)b * CL + q * 16) * NL + l0 + row;
        f16 tmp[16];
        #pragma unroll
        for (int i = 0; i < 16; ++i)
            tmp[i] = (f16)flb[(size_t)i * NL];
        #pragma unroll
        for (int j = 0; j < 2; ++j)
            *(f16x8*)&As[row * 392 + 256 + q * 16 + j * 8] =
                *(const f16x8*)&tmp[j * 8];
    }
    __syncthreads();

    f32x4 acc[2][4] = {};
    const int kb = (lane >> 4) * 8;
    const int r  = lane & 15;
    #pragma unroll
    for (int kt = 0; kt < 12; ++kt) {
        const int k0 = kt * 32;
        f16x8 a[2], bb[4];
        #pragma unroll
        for (int mi = 0; mi < 2; ++mi)
            a[mi] = *(const f16x8*)&Wh[(size_t)(w * 32 + mi * 16 + r) * CIN
                                       + k0 + kb];
        #pragma unroll
        for (int ni = 0; ni < 4; ++ni)
            bb[ni] = *(const f16x8*)&As[(ni * 16 + r) * 392 + k0 + kb];
        #pragma unroll
        for (int mi = 0; mi < 2; ++mi)
            #pragma unroll
            for (int ni = 0; ni < 4; ++ni)
                acc[mi][ni] = __builtin_amdgcn_mfma_f32_16x16x32_f16(
                    a[mi], bb[ni], acc[mi][ni], 0, 0, 0);
    }

    // bias into acc + per-block BN partials (no LDS touched)
    const int r4 = (lane >> 4) * 4, cl = lane & 15;
    #pragma unroll
    for (int mi = 0; mi < 2; ++mi) {
        #pragma unroll
        for (int j = 0; j < 4; ++j) {
            const int o = w * 32 + mi * 16 + r4 + j;
            const float bi = bias[o];
            float s = 0.0f, sq = 0.0f;
            #pragma unroll
            for (int ni = 0; ni < 4; ++ni) {
                acc[mi][ni][j] += bi;
                float v = acc[mi][ni][j];
                s += v; sq += v * v;
            }
            #pragma unroll
            for (int m = 1; m < 16; m <<= 1) {
                s  += __shfl_xor(s, m);
                sq += __shfl_xor(sq, m);
            }
            if (cl == 0) {
                ps [o * 512 + bid] = s;
                psq[o * 512 + bid] = sq;
            }
        }
    }
    __syncthreads();   // all As reads done -> safe to alias with Ys

    f16* Ys = (f16*)smraw;             // [256][72] f16 = 36864 B
    #pragma unroll
    for (int mi = 0; mi < 2; ++mi)
        #pragma unroll
        for (int j = 0; j < 4; ++j) {
            const int o = w * 32 + mi * 16 + r4 + j;
            #pragma unroll
            for (int ni = 0; ni < 4; ++ni)
                Ys[o * 72 + cl + ni * 16] = (f16)acc[mi][ni][j];
        }
    __syncthreads();
    {   // store: 2 threads per o-row -> 128B contiguous per row (no RMW)
        const int o = tid >> 1, half = tid & 1;
        f16* dst = yh + ((size_t)b * COUT + o) * NL + l0 + half * 32;
        #pragma unroll
        for (int j = 0; j < 4; ++j)
            *(f16x8*)(dst + j * 8) = *(const f16x8*)&Ys[o * 72 + half * 32 + j * 8];
    }
}

// ---------------------------------------------------------------------------
// K4: BN stats: reduce 512 partials per channel -> mean, rstd.
// ---------------------------------------------------------------------------
__global__ __launch_bounds__(256) void bn_stats_kernel(
    const float* __restrict__ ps, const float* __restrict__ psq,
    float* __restrict__ mean, float* __restrict__ rstd)
{
    const int o = blockIdx.x, tid = threadIdx.x;
    const int w = tid >> 6, lane = tid & 63;
    float s = ps[o * 512 + tid] + ps[o * 512 + 256 + tid];
    float q = psq[o * 512 + tid] + psq[o * 512 + 256 + tid];
    #pragma unroll
    for (int m = 32; m > 0; m >>= 1) {
        s += __shfl_down(s, m);
        q += __shfl_down(q, m);
    }
    __shared__ float red[8];
    if (lane == 0) { red[w] = s; red[4 + w] = q; }
    __syncthreads();
    if (tid == 0) {
        s = red[0] + red[1] + red[2] + red[3];
        q = red[4] + red[5] + red[6] + red[7];
        const float n = (float)(B_ * NL);
        const float m = s / n;
        mean[o] = m;
        rstd[o] = rsqrtf(q / n - m * m + 1e-5f);
    }
}

// ---------------------------------------------------------------------------
// K5: BN apply + ReLU: read yh fp16, write f32 d_out (overwrites the ficat
// scratch region — ficat is dead after K3).
// ---------------------------------------------------------------------------
__global__ __launch_bounds__(256) void bn_apply_kernel(
    const f16* __restrict__ yh, float* __restrict__ y,
    const float* __restrict__ mean, const float* __restrict__ rstd,
    const float* __restrict__ gamma, const float* __restrict__ beta)
{
    const size_t e8 = (size_t)blockIdx.x * 256 + threadIdx.x;
    const int oc = (int)((e8 >> 10) & (COUT - 1));             // NL/8 = 1024
    f16x8 v = ((const f16x8*)yh)[e8];
    const float m = mean[oc], rs = rstd[oc], g = gamma[oc], be = beta[oc];
    float4 o1, o2;
    o1.x = fmaxf(fmaf(g, ((float)v[0] - m) * rs, be), 0.0f);
    o1.y = fmaxf(fmaf(g, ((float)v[1] - m) * rs, be), 0.0f);
    o1.z = fmaxf(fmaf(g, ((float)v[2] - m) * rs, be), 0.0f);
    o1.w = fmaxf(fmaf(g, ((float)v[3] - m) * rs, be), 0.0f);
    o2.x = fmaxf(fmaf(g, ((float)v[4] - m) * rs, be), 0.0f);
    o2.y = fmaxf(fmaf(g, ((float)v[5] - m) * rs, be), 0.0f);
    o2.z = fmaxf(fmaf(g, ((float)v[6] - m) * rs, be), 0.0f);
    o2.w = fmaxf(fmaf(g, ((float)v[7] - m) * rs, be), 0.0f);
    ((float4*)y)[e8 * 2]     = o1;
    ((float4*)y)[e8 * 2 + 1] = o2;
}

// ---------------------------------------------------------------------------
extern "C" void kernel_launch(void* const* d_in, const int* in_sizes, int n_in,
                              void* d_out, int out_size, void* d_ws, size_t ws_size,
                              hipStream_t stream)
{
    const float* xyz_low   = (const float*)d_in[0];
    const float* xyz_high  = (const float*)d_in[1];
    const float* feat_low  = (const float*)d_in[2];
    const float* feat_high = (const float*)d_in[3];
    const float* Wm        = (const float*)d_in[4];
    const float* bias      = (const float*)d_in[5];
    const float* gamma     = (const float*)d_in[6];
    const float* beta      = (const float*)d_in[7];
    float* y = (float*)d_out;

    float* ps   = (float*)d_ws;                        // 256*512 f32
    float* psq  = ps + (size_t)COUT * 512;             // 256*512 f32
    float* mean = psq + (size_t)COUT * 512;            // 256
    float* rstd = mean + COUT;                         // 256 (+256 pad)
    float* cdG  = rstd + COUT + 256;                   // 2048*192 f32
    int*   ciG  = (int*)(cdG + (size_t)2048 * 192);    // 2048*192 i32
    f16*   Wh   = (f16*)(ciG + (size_t)2048 * 192);    // 256*384 f16
    f16*   fhT  = Wh + (size_t)COUT * CIN;             // 4*2048*256 f16 (4.2MB)
    f16*   yh   = fhT + (size_t)B_ * NH * CH;          // 4*256*8192 f16 (16.8MB)
    f16*   ficat = (f16*)d_out;                        // scratch: dead by K5

    knn_prep_kernel<<<2944, 256, 0, stream>>>(
        xyz_low, xyz_high, feat_high, Wm, fhT, Wh, cdG, ciG);
    interp_kernel<<<2048, 256, 0, stream>>>(fhT, cdG, ciG, ficat);
    gemm_kernel<<<512, 512, 0, stream>>>(
        feat_low, ficat, Wh, bias, yh, ps, psq);
    bn_stats_kernel<<<COUT, 256, 0, stream>>>(ps, psq, mean, rstd);
    bn_apply_kernel<<<(int)((size_t)B_ * COUT * NL / 8 / 256), 256, 0, stream>>>(
        yh, y, mean, rstd, gamma, beta);
}